// Round 3
// baseline (744.024 us; speedup 1.0000x reference)
//
#include <hip/hip_runtime.h>

#define BB 32
#define CC 256
#define HH 64
#define WW 64
#define O1 16

// K0: transpose w1 [16][256][3][3] -> w1t [256][3][3][16] so the 16 output-
// channel weights for a fixed (c,kh,kw) are contiguous (enables s_load_dwordx
// wave-uniform reads in conv1's inner loop).
__global__ __launch_bounds__(256) void k_w1t(const float* __restrict__ w1,
                                             float* __restrict__ w1t) {
    int i = blockIdx.x * 256 + threadIdx.x;   // 0 .. 36863
    if (i >= O1 * CC * 9) return;
    int o  = i & 15;
    int t  = i >> 4;          // (c*3+kh)*3+kw
    int kw = t % 3;
    int t2 = t / 3;
    int kh = t2 % 3;
    int c  = t2 / 3;
    w1t[i] = w1[((o * CC + c) * 3 + kh) * 3 + kw];
}

// K1: t = relu(conv1(x_in, w1)), pad 1.  Block = (b, 4 output rows).
// 256 threads = 4 rows x 64 w, one pixel per thread, 16 fp32 accumulators.
// x staged in LDS in 8-channel chunks (6 input rows x 66 padded cols).
// Weight indices are wave-uniform -> scalar loads.
__global__ __launch_bounds__(256) void k_conv1(const float* __restrict__ x,
                                               const float* __restrict__ w1t,
                                               float* __restrict__ t) {
    __shared__ float xs[8][6][66];
    const int b   = blockIdx.x >> 4;
    const int h0  = (blockIdx.x & 15) << 2;
    const int tid = threadIdx.x;
    const int r   = tid >> 6;      // 0..3
    const int w   = tid & 63;

    float acc[16];
#pragma unroll
    for (int o = 0; o < 16; ++o) acc[o] = 0.f;

    const float* xb = x + (size_t)b * CC * HH * WW;

    for (int chunk = 0; chunk < 32; ++chunk) {
        const int c0 = chunk * 8;
        // stage 8 channels x 6 rows x 64 cols (float4 units: 768 total, 3/thread)
#pragma unroll
        for (int i = 0; i < 3; ++i) {
            int idx4 = i * 256 + tid;
            int cc   = idx4 / 96;
            int rem  = idx4 - cc * 96;
            int rr   = rem >> 4;            // 0..5
            int w4   = (rem & 15) << 2;     // 0..60
            int hh   = h0 - 1 + rr;
            float4 v = make_float4(0.f, 0.f, 0.f, 0.f);
            if (hh >= 0 && hh < HH)
                v = *reinterpret_cast<const float4*>(xb + ((size_t)(c0 + cc) * HH + hh) * WW + w4);
            xs[cc][rr][w4 + 1] = v.x;
            xs[cc][rr][w4 + 2] = v.y;
            xs[cc][rr][w4 + 3] = v.z;
            xs[cc][rr][w4 + 4] = v.w;
        }
        if (tid < 48) {          // zero the left/right pad columns
            int cc = tid / 6, rr = tid % 6;
            xs[cc][rr][0]  = 0.f;
            xs[cc][rr][65] = 0.f;
        }
        __syncthreads();

#pragma unroll
        for (int cc = 0; cc < 8; ++cc) {
#pragma unroll
            for (int kh = 0; kh < 3; ++kh) {
                float x0 = xs[cc][r + kh][w];       // x[h+kh-1][w-1]
                float x1 = xs[cc][r + kh][w + 1];   // x[h+kh-1][w  ]
                float x2 = xs[cc][r + kh][w + 2];   // x[h+kh-1][w+1]
                const float* wp = w1t + ((size_t)(c0 + cc) * 3 + kh) * 48;
#pragma unroll
                for (int o = 0; o < 16; ++o) {
                    acc[o] += wp[o] * x0 + wp[16 + o] * x1 + wp[32 + o] * x2;
                }
            }
        }
        __syncthreads();
    }

    const int h = h0 + r;
    float* tb = t + (size_t)b * O1 * HH * WW + h * WW + w;
#pragma unroll
    for (int o = 0; o < 16; ++o) tb[(size_t)o * HH * WW] = fmaxf(acc[o], 0.f);
}

// K2: A = sigmoid(conv2(t, w2)), pad 1.  One pixel per thread; t reads hit L1/L2.
__global__ __launch_bounds__(256) void k_conv2(const float* __restrict__ t,
                                               const float* __restrict__ w2,
                                               float* __restrict__ A) {
    const int b   = blockIdx.x >> 4;
    const int h0  = (blockIdx.x & 15) << 2;
    const int tid = threadIdx.x;
    const int h   = h0 + (tid >> 6);
    const int w   = tid & 63;
    const float* tb = t + (size_t)b * O1 * HH * WW;
    float s = 0.f;
#pragma unroll
    for (int c = 0; c < 16; ++c) {
#pragma unroll
        for (int kh = 0; kh < 3; ++kh) {
            int hh = h + kh - 1;
            if (hh < 0 || hh >= HH) continue;
            const float* row = tb + ((size_t)c * HH + hh) * WW;
#pragma unroll
            for (int kw = 0; kw < 3; ++kw) {
                int ww = w + kw - 1;
                if (ww < 0 || ww >= WW) continue;
                s += w2[(c * 3 + kh) * 3 + kw] * row[ww];
            }
        }
    }
    A[(size_t)b * HH * WW + h * WW + w] = 1.f / (1.f + expf(-s));
}

// K3: A_box = 3x3 zero-padded box sum of A.
__global__ __launch_bounds__(256) void k_box(const float* __restrict__ A,
                                             float* __restrict__ Ab) {
    const int b   = blockIdx.x >> 4;
    const int h0  = (blockIdx.x & 15) << 2;
    const int tid = threadIdx.x;
    const int h   = h0 + (tid >> 6);
    const int w   = tid & 63;
    const float* Ap = A + (size_t)b * HH * WW;
    float s = 0.f;
#pragma unroll
    for (int kh = -1; kh <= 1; ++kh) {
        int hh = h + kh;
        if (hh < 0 || hh >= HH) continue;
#pragma unroll
        for (int kw = -1; kw <= 1; ++kw) {
            int ww = w + kw;
            if (ww < 0 || ww >= WW) continue;
            s += Ap[hh * WW + ww];
        }
    }
    Ab[(size_t)b * HH * WW + h * WW + w] = s;
}

// K4: out = x_out * A_box (broadcast over C).  float4 grid-stride.
__global__ __launch_bounds__(256) void k_mul(const float* __restrict__ xo,
                                             const float* __restrict__ Ab,
                                             float* __restrict__ out, int n4) {
    const int stride = gridDim.x * blockDim.x;
    for (int i = blockIdx.x * blockDim.x + threadIdx.x; i < n4; i += stride) {
        int flat = i << 2;
        int s    = flat & 4095;        // h*64+w (4 consecutive w, no row cross)
        int bi   = flat >> 20;         // / (256*4096)
        float4 a = *reinterpret_cast<const float4*>(Ab + (size_t)bi * 4096 + s);
        float4 v = reinterpret_cast<const float4*>(xo)[i];
        float4 r;
        r.x = v.x * a.x; r.y = v.y * a.y; r.z = v.z * a.z; r.w = v.w * a.w;
        reinterpret_cast<float4*>(out)[i] = r;
    }
}

extern "C" void kernel_launch(void* const* d_in, const int* in_sizes, int n_in,
                              void* d_out, int out_size, void* d_ws, size_t ws_size,
                              hipStream_t stream) {
    const float* x_in  = (const float*)d_in[0];
    const float* x_out = (const float*)d_in[1];
    const float* w1    = (const float*)d_in[2];
    const float* w2    = (const float*)d_in[3];
    // fc1/fc2 (d_in[4], d_in[5]) are dead code in the reference.

    float* ws  = (float*)d_ws;
    float* w1t = ws;                        // 36864 floats
    float* t   = ws + 36864;                // 2097152 floats
    float* A   = t + 2097152;               // 131072 floats
    float* Ab  = A + 131072;                // 131072 floats
    float* out = (float*)d_out;

    hipLaunchKernelGGL(k_w1t,   dim3(144),  dim3(256), 0, stream, w1, w1t);
    hipLaunchKernelGGL(k_conv1, dim3(512),  dim3(256), 0, stream, x_in, w1t, t);
    hipLaunchKernelGGL(k_conv2, dim3(512),  dim3(256), 0, stream, t, w2, A);
    hipLaunchKernelGGL(k_box,   dim3(512),  dim3(256), 0, stream, A, Ab);
    hipLaunchKernelGGL(k_mul,   dim3(2048), dim3(256), 0, stream, x_out, Ab, out,
                       (BB * CC * HH * WW) / 4);
}

// Round 4
// 339.799 us; speedup vs baseline: 2.1896x; 2.1896x over previous
//
#include <hip/hip_runtime.h>

typedef __attribute__((ext_vector_type(8))) short bf16x8;
typedef __attribute__((ext_vector_type(4))) float f32x4;

#define BB 32
#define CC 256
#define HH 64
#define WW 64
#define O1 16

__device__ __forceinline__ ushort f2bf(float f) {
    uint v = __float_as_uint(f);
    v = (v + 0x7FFFu + ((v >> 16) & 1u)) >> 16;   // round-to-nearest-even
    return (ushort)v;
}

// Pack w1 [16o][256c][3][3] fp32 -> wb [tap][c/8][16o][c%8] bf16 so a lane's
// B-fragment (o = lane&15, c = cgrp*8..+7) is one contiguous 16B load.
__global__ __launch_bounds__(256) void k_wprep(const float* __restrict__ w1,
                                               ushort* __restrict__ wb) {
    int i = blockIdx.x * 256 + threadIdx.x;
    if (i >= 9 * 32 * 16 * 8) return;
    int c8   = i & 7;
    int o    = (i >> 3) & 15;
    int cgrp = (i >> 7) & 31;
    int tap  = i >> 12;            // kh*3+kw
    int c    = cgrp * 8 + c8;
    wb[i] = f2bf(w1[(o * CC + c) * 9 + tap]);
}

// conv1 as implicit GEMM on MFMA 16x16x32 bf16.
// Block: (batch b, 4 output rows h0..h0+3, C-split sp of 128 channels).
// 4 waves; wave r owns output row h0+r (64 pixels = 4 M-fragments).
// LDS tile: [6 rows][66 cols][32 ch] bf16, pixel-major, 16B-quad XOR swizzle:
//   byte(pix, ci) = pix*64 + ((quad(ci) ^ ((pix>>1)&3))<<4) + (ci&7)*2
// K-loop: 4 chunks of 32 channels x 9 taps; A-frag = shifted ds_read_b128.
__global__ __launch_bounds__(256, 4) void k_conv1m(const float* __restrict__ x,
                                                   const ushort* __restrict__ wb,
                                                   ushort* __restrict__ tp) {
    __shared__ uint xs[6 * 66 * 16];          // 25,344 B
    char* xsb = (char*)xs;
    const int bid = blockIdx.x;
    const int sp  = bid & 1;
    const int hg  = (bid >> 1) & 15;
    const int b   = bid >> 5;
    const int h0  = hg << 2;
    const int tid  = threadIdx.x;
    const int wave = tid >> 6;
    const int lane = tid & 63;
    const int l15  = lane & 15;
    const int slot = lane >> 4;

    // zero the w-pad columns (wl=0,65) once; never overwritten after.
    if (tid < 192) {
        int col = (tid & 1) * 65;
        int cp  = (tid >> 1) & 15;
        int rr  = tid >> 5;
        int ci  = cp << 1;
        int pix = rr * 66 + col;
        int byt = pix * 64 + ((((ci >> 3) ^ ((pix >> 1) & 3)) << 4) | ((ci & 7) << 1));
        *(uint*)(xsb + byt) = 0u;
    }

    f32x4 acc[4];
#pragma unroll
    for (int m = 0; m < 4; ++m) acc[m] = (f32x4){0.f, 0.f, 0.f, 0.f};

    const float* xb = x + (size_t)b * CC * HH * WW;

    for (int ck = 0; ck < 4; ++ck) {
        const int cbase = sp * 128 + ck * 32;
        __syncthreads();   // previous chunk's compute done before overwrite
        // ---- stage 6x64x32 fp32 -> bf16 LDS (pixel-major), 12 units/thread
#pragma unroll
        for (int it = 0; it < 12; ++it) {
            int unit = it * 256 + tid;       // (rr 0..5)(cp 0..15)(w2 0..31)
            int w2i  = unit & 31;
            int rest = unit >> 5;
            int rr   = rest >> 4;
            int cp   = rest & 15;
            int ci   = cp << 1;
            int w    = w2i << 1;
            int hh   = h0 - 1 + rr;
            float2 a = make_float2(0.f, 0.f), c2 = make_float2(0.f, 0.f);
            if (hh >= 0 && hh < HH) {
                const float* p = xb + (size_t)(cbase + ci) * (HH * WW) + hh * WW + w;
                a  = *(const float2*)p;
                c2 = *(const float2*)(p + HH * WW);
            }
            uint u0 = (uint)f2bf(a.x) | ((uint)f2bf(c2.x) << 16);
            uint u1 = (uint)f2bf(a.y) | ((uint)f2bf(c2.y) << 16);
            int pix0 = rr * 66 + w + 1;
            int pix1 = pix0 + 1;
            int b0 = pix0 * 64 + ((((ci >> 3) ^ ((pix0 >> 1) & 3)) << 4) | ((ci & 7) << 1));
            int b1 = pix1 * 64 + ((((ci >> 3) ^ ((pix1 >> 1) & 3)) << 4) | ((ci & 7) << 1));
            *(uint*)(xsb + b0) = u0;
            *(uint*)(xsb + b1) = u1;
        }
        __syncthreads();

        // ---- B fragments for the 9 taps of this 32-channel chunk
        bf16x8 bfrag[9];
#pragma unroll
        for (int tap = 0; tap < 9; ++tap) {
            const ushort* wp = wb + (((size_t)(tap * 32 + (cbase >> 3) + slot) * 16 + l15) << 3);
            bfrag[tap] = *(const bf16x8*)wp;
        }

        // ---- 9 taps x 4 M-frags: ds_read_b128 + MFMA
#pragma unroll
        for (int dy = 0; dy < 3; ++dy) {
#pragma unroll
            for (int dx = 0; dx < 3; ++dx) {
                const int tap = dy * 3 + dx;
#pragma unroll
                for (int m = 0; m < 4; ++m) {
                    int pix = (wave + dy) * 66 + m * 16 + l15 + dx;
                    int byt = pix * 64 + ((slot ^ ((pix >> 1) & 3)) << 4);
                    bf16x8 af = *(const bf16x8*)(xsb + byt);
                    acc[m] = __builtin_amdgcn_mfma_f32_16x16x32_bf16(af, bfrag[tap], acc[m], 0, 0, 0);
                }
            }
        }
    }

    // ---- epilogue: bf16 partials, NHWC-16: tp[sp][b][h][w][o]
    ushort* tps = tp + (size_t)sp * (BB * HH * WW * O1);
    const int h = h0 + wave;
#pragma unroll
    for (int m = 0; m < 4; ++m) {
#pragma unroll
        for (int r = 0; r < 4; ++r) {
            int w = m * 16 + slot * 4 + r;            // D row = pixel
            tps[(((size_t)b * HH + h) * WW + w) * O1 + l15] = f2bf(acc[m][r]);
        }
    }
}

// conv2: A = sigmoid( sum_{c,tap} w2 * relu(t0+t1) ), t in NHWC-16 bf16.
__global__ __launch_bounds__(256) void k_conv2(const ushort* __restrict__ tp,
                                               const float* __restrict__ w2,
                                               float* __restrict__ A) {
    const int b  = blockIdx.x >> 4;
    const int h0 = (blockIdx.x & 15) << 2;
    const int h  = h0 + (threadIdx.x >> 6);
    const int w  = threadIdx.x & 63;
    const ushort* t0 = tp;
    const ushort* t1 = tp + (size_t)BB * HH * WW * O1;
    float s = 0.f;
    for (int dy = 0; dy < 3; ++dy) {
        int hh = h + dy - 1;
        if (hh < 0 || hh >= HH) continue;
        for (int dx = 0; dx < 3; ++dx) {
            int ww = w + dx - 1;
            if (ww < 0 || ww >= WW) continue;
            int tap = dy * 3 + dx;
            size_t base = (((size_t)b * HH + hh) * WW + ww) * O1;
            uint4 p0 = *(const uint4*)(t0 + base);
            uint4 p1 = *(const uint4*)(t0 + base + 8);
            uint4 q0 = *(const uint4*)(t1 + base);
            uint4 q1 = *(const uint4*)(t1 + base + 8);
            uint pa[8] = {p0.x, p0.y, p0.z, p0.w, p1.x, p1.y, p1.z, p1.w};
            uint qa[8] = {q0.x, q0.y, q0.z, q0.w, q1.x, q1.y, q1.z, q1.w};
#pragma unroll
            for (int u = 0; u < 8; ++u) {
                float v0 = __uint_as_float((pa[u] & 0xFFFFu) << 16) +
                           __uint_as_float((qa[u] & 0xFFFFu) << 16);
                float v1 = __uint_as_float(pa[u] & 0xFFFF0000u) +
                           __uint_as_float(qa[u] & 0xFFFF0000u);
                v0 = fmaxf(v0, 0.f);
                v1 = fmaxf(v1, 0.f);
                s += w2[(2 * u) * 9 + tap] * v0 + w2[(2 * u + 1) * 9 + tap] * v1;
            }
        }
    }
    A[((size_t)b * HH + h) * WW + w] = 1.f / (1.f + __expf(-s));
}

// A_box = 3x3 zero-padded box sum of A.
__global__ __launch_bounds__(256) void k_box(const float* __restrict__ A,
                                             float* __restrict__ Ab) {
    const int b   = blockIdx.x >> 4;
    const int h0  = (blockIdx.x & 15) << 2;
    const int tid = threadIdx.x;
    const int h   = h0 + (tid >> 6);
    const int w   = tid & 63;
    const float* Ap = A + (size_t)b * HH * WW;
    float s = 0.f;
#pragma unroll
    for (int kh = -1; kh <= 1; ++kh) {
        int hh = h + kh;
        if (hh < 0 || hh >= HH) continue;
#pragma unroll
        for (int kw = -1; kw <= 1; ++kw) {
            int ww = w + kw;
            if (ww < 0 || ww >= WW) continue;
            s += Ap[hh * WW + ww];
        }
    }
    Ab[(size_t)b * HH * WW + h * WW + w] = s;
}

// out = x_out * A_box (broadcast over C).  float4 grid-stride.
__global__ __launch_bounds__(256) void k_mul(const float* __restrict__ xo,
                                             const float* __restrict__ Ab,
                                             float* __restrict__ out, int n4) {
    const int stride = gridDim.x * blockDim.x;
    for (int i = blockIdx.x * blockDim.x + threadIdx.x; i < n4; i += stride) {
        int flat = i << 2;
        int s    = flat & 4095;
        int bi   = flat >> 20;
        float4 a = *reinterpret_cast<const float4*>(Ab + (size_t)bi * 4096 + s);
        float4 v = reinterpret_cast<const float4*>(xo)[i];
        float4 r;
        r.x = v.x * a.x; r.y = v.y * a.y; r.z = v.z * a.z; r.w = v.w * a.w;
        reinterpret_cast<float4*>(out)[i] = r;
    }
}

extern "C" void kernel_launch(void* const* d_in, const int* in_sizes, int n_in,
                              void* d_out, int out_size, void* d_ws, size_t ws_size,
                              hipStream_t stream) {
    const float* x_in  = (const float*)d_in[0];
    const float* x_out = (const float*)d_in[1];
    const float* w1    = (const float*)d_in[2];
    const float* w2    = (const float*)d_in[3];
    // fc1/fc2 are dead code in the reference.

    ushort* wb = (ushort*)d_ws;                           // 36,864 ushort (73,728 B)
    ushort* tp = wb + 36864;                              // 2 x 2,097,152 ushort (8.39 MB)
    float*  A  = (float*)((char*)d_ws + 73728 + 8388608); // 131,072 f32
    float*  Ab = A + 131072;                              // 131,072 f32
    float*  out = (float*)d_out;

    hipLaunchKernelGGL(k_wprep,  dim3(144),  dim3(256), 0, stream, w1, wb);
    hipLaunchKernelGGL(k_conv1m, dim3(1024), dim3(256), 0, stream, x_in, wb, tp);
    hipLaunchKernelGGL(k_conv2,  dim3(512),  dim3(256), 0, stream, tp, w2, A);
    hipLaunchKernelGGL(k_box,    dim3(512),  dim3(256), 0, stream, A, Ab);
    hipLaunchKernelGGL(k_mul,    dim3(2048), dim3(256), 0, stream, x_out, Ab, out,
                       (BB * CC * HH * WW) / 4);
}